// Round 1
// baseline (150.638 us; speedup 1.0000x reference)
//
#include <hip/hip_runtime.h>
#include <hip/hip_bf16.h>
#include <stdint.h>

typedef __bf16 bf16;
typedef __bf16 bf16x8 __attribute__((ext_vector_type(8)));
typedef __bf16 bf16x4 __attribute__((ext_vector_type(4)));
typedef float  f32x4  __attribute__((ext_vector_type(4)));
typedef unsigned int u32;

typedef __attribute__((address_space(1))) u32 gu32;
typedef __attribute__((address_space(3))) u32 lu32;

// global -> LDS direct load, 16B per lane. LDS dest is wave-uniform base + lane*16.
__device__ __forceinline__ void gld_lds16(const void* g, void* l) {
  __builtin_amdgcn_global_load_lds((gu32*)(uintptr_t)g, (lu32*)(u32)(uintptr_t)l, 16, 0, 0);
}

__device__ __forceinline__ f32x4 mfma_bf16_16x16x32(bf16x8 a, bf16x8 b, f32x4 c) {
  return __builtin_amdgcn_mfma_f32_16x16x32_bf16(a, b, c, 0, 0, 0);
}

// ---------------- cast x (fp32 -> bf16), 8 elems/thread ----------------
__global__ __launch_bounds__(256) void k_cast_x(const float* __restrict__ x,
                                                bf16* __restrict__ xb) {
  size_t i = (size_t)blockIdx.x * 256 + threadIdx.x;   // 2,097,152 threads
  const float4* p = (const float4*)x + i * 2;
  float4 a = p[0], b = p[1];
  bf16x8 o;
  o[0] = (bf16)a.x; o[1] = (bf16)a.y; o[2] = (bf16)a.z; o[3] = (bf16)a.w;
  o[4] = (bf16)b.x; o[5] = (bf16)b.y; o[6] = (bf16)b.z; o[7] = (bf16)b.w;
  *(bf16x8*)(xb + i * 8) = o;
}

// ---------------- transpose w [512][1536] f32 -> wT [1536][512] bf16 ----------------
__global__ __launch_bounds__(256) void k_prep_w(const float* __restrict__ w,
                                                bf16* __restrict__ wT) {
  int idx = blockIdx.x * 256 + threadIdx.x;  // 786432
  int n = idx >> 9;
  int k = idx & 511;
  wT[idx] = (bf16)w[k * 1536 + n];
}

// ---------------- QKV GEMM (128x128 tile, BK=64) + fused LayerNorm epilogue ----
// A = xb [32768][512], Bt = wT [1536][512].
// Epilogue: cols 0-511 -> q (LN) stored [bh][n][d]; 512-1023 -> k (LN) stored
// transposed [bh][d][n]; 1024-1535 -> v stored transposed [bh][d][n].
__global__ __launch_bounds__(256) void k_qkv_gemm(
    const bf16* __restrict__ A, const bf16* __restrict__ Bt,
    const float* __restrict__ qg, const float* __restrict__ qbeta,
    const float* __restrict__ kg, const float* __restrict__ kbeta,
    bf16* __restrict__ qh, bf16* __restrict__ kt, bf16* __restrict__ vt)
{
  __shared__ bf16 lA[128 * 64];
  __shared__ bf16 lB[128 * 64];
  const int tid = threadIdx.x;
  const int lane = tid & 63;
  const int w = tid >> 6;
  const int wm = w >> 1, wn = w & 1;
  const int tm = blockIdx.y, tn = blockIdx.x;

  f32x4 acc[4][4] = {};

  // swizzled staging: LDS block p at row r holds source 16B-block p ^ (r&7)
  const int srow = lane >> 3;          // row within 1KB slot
  const int sblk = (lane & 7) ^ srow;  // source 16B block index

  for (int ktile = 0; ktile < 8; ++ktile) {
    __syncthreads();
#pragma unroll
    for (int i = 0; i < 4; ++i) {
      int slot = w * 4 + i;
      int row = slot * 8 + srow;
      gld_lds16(A  + (size_t)(tm * 128 + row) * 512 + ktile * 64 + sblk * 8,
                (char*)lA + slot * 1024);
      gld_lds16(Bt + (size_t)(tn * 128 + row) * 512 + ktile * 64 + sblk * 8,
                (char*)lB + slot * 1024);
    }
    __syncthreads();
#pragma unroll
    for (int ks = 0; ks < 2; ++ks) {
      bf16x8 af[4], bq[4];
#pragma unroll
      for (int f = 0; f < 4; ++f) {
        int rowa = wm * 64 + f * 16 + (lane & 15);
        int sba = (ks * 4 + (lane >> 4)) ^ (rowa & 7);
        af[f] = *(const bf16x8*)(lA + rowa * 64 + sba * 8);
        int rowb = wn * 64 + f * 16 + (lane & 15);
        int sbb = (ks * 4 + (lane >> 4)) ^ (rowb & 7);
        bq[f] = *(const bf16x8*)(lB + rowb * 64 + sbb * 8);
      }
#pragma unroll
      for (int fm = 0; fm < 4; ++fm)
#pragma unroll
        for (int fn = 0; fn < 4; ++fn)
          acc[fm][fn] = mfma_bf16_16x16x32(af[fm], bq[fn], acc[fm][fn]);
    }
  }

  // ---- epilogue ----
  const int colbase = tn * 128 + wn * 64;   // wave's 64-col quadrant = one head
  const int part = colbase >> 9;            // 0=q 1=k 2=v
  const int hcol = (colbase & 511) >> 6;    // head index
  const int dlane = lane & 15;
  const int rsub = (lane >> 4) * 4;

  if (part == 2) {  // v: no LN, store transposed [bh][d][n]
#pragma unroll
    for (int fm = 0; fm < 4; ++fm) {
      int rowg = tm * 128 + wm * 64 + fm * 16 + rsub;
      int bb = rowg >> 12, n0 = rowg & 4095;
      size_t bh64 = (size_t)(bb * 8 + hcol) * 64;
#pragma unroll
      for (int fn = 0; fn < 4; ++fn) {
        bf16x4 pk;
#pragma unroll
        for (int r = 0; r < 4; ++r) pk[r] = (bf16)acc[fm][fn][r];
        *(bf16x4*)(vt + (bh64 + fn * 16 + dlane) * 4096 + n0) = pk;
      }
    }
  } else {
    const float* gamma = (part == 0) ? qg : kg;
    const float* beta  = (part == 0) ? qbeta : kbeta;
    float g4[4], b4[4];
#pragma unroll
    for (int fn = 0; fn < 4; ++fn) {
      g4[fn] = gamma[fn * 16 + dlane];
      b4[fn] = beta[fn * 16 + dlane];
    }
#pragma unroll
    for (int fm = 0; fm < 4; ++fm) {
      float mu[4], rs[4];
#pragma unroll
      for (int r = 0; r < 4; ++r) {  // per-row LN stats: 4 fn + 16-lane shfl reduce
        float s  = acc[fm][0][r] + acc[fm][1][r] + acc[fm][2][r] + acc[fm][3][r];
        float s2 = acc[fm][0][r] * acc[fm][0][r] + acc[fm][1][r] * acc[fm][1][r]
                 + acc[fm][2][r] * acc[fm][2][r] + acc[fm][3][r] * acc[fm][3][r];
#pragma unroll
        for (int m = 1; m < 16; m <<= 1) {
          s  += __shfl_xor(s, m, 64);
          s2 += __shfl_xor(s2, m, 64);
        }
        float mean = s * (1.0f / 64.0f);
        float var  = s2 * (1.0f / 64.0f) - mean * mean;
        mu[r] = mean;
        rs[r] = rsqrtf(var + 1e-5f);
      }
      int rowg = tm * 128 + wm * 64 + fm * 16 + rsub;
      int bb = rowg >> 12, n0 = rowg & 4095;
      int bh = bb * 8 + hcol;
      if (part == 0) {  // q: store [bh][n][d]
        bf16* dst = qh + ((size_t)bh * 4096 + n0) * 64;
#pragma unroll
        for (int r = 0; r < 4; ++r)
#pragma unroll
          for (int fn = 0; fn < 4; ++fn) {
            float xv = (acc[fm][fn][r] - mu[r]) * rs[r] * g4[fn] + b4[fn];
            dst[(size_t)r * 64 + fn * 16 + dlane] = (bf16)xv;
          }
      } else {  // k: LN then store transposed [bh][d][n]
#pragma unroll
        for (int fn = 0; fn < 4; ++fn) {
          bf16x4 pk;
#pragma unroll
          for (int r = 0; r < 4; ++r)
            pk[r] = (bf16)((acc[fm][fn][r] - mu[r]) * rs[r] * g4[fn] + b4[fn]);
          *(bf16x4*)(kt + ((size_t)bh * 64 + fn * 16 + dlane) * 4096 + n0) = pk;
        }
      }
    }
  }
}

// ---------------- dots^T = V^T K per (b,h), split-K=16, deterministic partials ----
// A = vt rows [e][n], BT = kt rows [d][n]; D[e][d] = sum_n v[n][e] k[n][d]
__global__ __launch_bounds__(64) void k_dots(const bf16* __restrict__ vt,
                                             const bf16* __restrict__ kt,
                                             float* __restrict__ dTp) {
  __shared__ bf16 lA[64 * 64];
  __shared__ bf16 lB[64 * 64];
  const int lane = threadIdx.x;
  const int bh = blockIdx.y, ch = blockIdx.x;
  const bf16* Ab = vt + (size_t)bh * 64 * 4096 + ch * 256;
  const bf16* Bb = kt + (size_t)bh * 64 * 4096 + ch * 256;
  f32x4 acc[4][4] = {};
  const int srow = lane >> 3;
  const int sblk = (lane & 7) ^ srow;
  for (int ktile = 0; ktile < 4; ++ktile) {
    __syncthreads();
#pragma unroll
    for (int i = 0; i < 8; ++i) {
      int row = i * 8 + srow;
      gld_lds16(Ab + (size_t)row * 4096 + ktile * 64 + sblk * 8, (char*)lA + i * 1024);
      gld_lds16(Bb + (size_t)row * 4096 + ktile * 64 + sblk * 8, (char*)lB + i * 1024);
    }
    __syncthreads();
#pragma unroll
    for (int ks = 0; ks < 2; ++ks) {
      bf16x8 af[4], bq[4];
#pragma unroll
      for (int f = 0; f < 4; ++f) {
        int row = f * 16 + (lane & 15);
        int sb = (ks * 4 + (lane >> 4)) ^ (row & 7);
        af[f] = *(const bf16x8*)(lA + row * 64 + sb * 8);
        bq[f] = *(const bf16x8*)(lB + row * 64 + sb * 8);
      }
#pragma unroll
      for (int fm = 0; fm < 4; ++fm)
#pragma unroll
        for (int fn = 0; fn < 4; ++fn)
          acc[fm][fn] = mfma_bf16_16x16x32(af[fm], bq[fn], acc[fm][fn]);
    }
  }
  float* outp = dTp + (size_t)ch * 262144 + (size_t)bh * 4096;
#pragma unroll
  for (int fm = 0; fm < 4; ++fm)
#pragma unroll
    for (int fn = 0; fn < 4; ++fn)
#pragma unroll
      for (int r = 0; r < 4; ++r) {
        int e = fm * 16 + (lane >> 4) * 4 + r;
        int d = fn * 16 + (lane & 15);
        outp[e * 64 + d] = acc[fm][fn][r];
      }
}

// ---------------- reduce split-K partials, cast to bf16 ----------------
__global__ __launch_bounds__(256) void k_cvt_dt(const float* __restrict__ dTp,
                                                bf16* __restrict__ dTb) {
  int i = blockIdx.x * 256 + threadIdx.x;  // 262144
  float s = 0.f;
#pragma unroll
  for (int c = 0; c < 16; ++c) s += dTp[(size_t)c * 262144 + i];
  dTb[i] = (bf16)s;
}

// ---------------- out = (Q @ dots) / n ; A = qh [bh][n][d], BT = dTb [bh][e][d] ----
__global__ __launch_bounds__(256) void k_out(const bf16* __restrict__ qh,
                                             const bf16* __restrict__ dTb,
                                             float* __restrict__ out) {
  __shared__ bf16 lA[128 * 64];
  const int tid = threadIdx.x, lane = tid & 63, w = tid >> 6;
  const int wm = w >> 1, wn = w & 1;
  const int bh = blockIdx.y, mt = blockIdx.x;
  const int bb = bh >> 3, h = bh & 7;
  const bf16* Ab = qh + (size_t)bh * 4096 * 64 + (size_t)mt * 128 * 64;
  const int srow = lane >> 3, sblk = (lane & 7) ^ srow;
#pragma unroll
  for (int i = 0; i < 4; ++i) {
    int slot = w * 4 + i;
    int row = slot * 8 + srow;
    gld_lds16(Ab + (size_t)row * 64 + sblk * 8, (char*)lA + slot * 1024);
  }
  __syncthreads();
  const bf16* Bb = dTb + (size_t)bh * 4096;
  f32x4 acc[4][2] = {};
#pragma unroll
  for (int ks = 0; ks < 2; ++ks) {
    bf16x8 af[4], bq[2];
#pragma unroll
    for (int f = 0; f < 4; ++f) {
      int row = wm * 64 + f * 16 + (lane & 15);
      int sb = (ks * 4 + (lane >> 4)) ^ (row & 7);
      af[f] = *(const bf16x8*)(lA + row * 64 + sb * 8);
    }
#pragma unroll
    for (int fn = 0; fn < 2; ++fn) {
      int e = wn * 32 + fn * 16 + (lane & 15);
      bq[fn] = *(const bf16x8*)(Bb + e * 64 + ks * 32 + (lane >> 4) * 8);
    }
#pragma unroll
    for (int fm = 0; fm < 4; ++fm)
#pragma unroll
      for (int fn = 0; fn < 2; ++fn)
        acc[fm][fn] = mfma_bf16_16x16x32(af[fm], bq[fn], acc[fm][fn]);
  }
#pragma unroll
  for (int fm = 0; fm < 4; ++fm)
#pragma unroll
    for (int fn = 0; fn < 2; ++fn)
#pragma unroll
      for (int r = 0; r < 4; ++r) {
        int n = mt * 128 + wm * 64 + fm * 16 + (lane >> 4) * 4 + r;
        int e = wn * 32 + fn * 16 + (lane & 15);
        out[((size_t)bb * 4096 + n) * 512 + h * 64 + e] = acc[fm][fn][r] * (1.0f / 4096.0f);
      }
}

extern "C" void kernel_launch(void* const* d_in, const int* in_sizes, int n_in,
                              void* d_out, int out_size, void* d_ws, size_t ws_size,
                              hipStream_t stream) {
  const float* x  = (const float*)d_in[0];
  const float* wq = (const float*)d_in[1];
  const float* qg = (const float*)d_in[2];
  const float* qb = (const float*)d_in[3];
  const float* kg = (const float*)d_in[4];
  const float* kb = (const float*)d_in[5];
  float* out = (float*)d_out;
  char* ws = (char*)d_ws;

  // workspace layout (130 MB total):
  bf16* xb = (bf16*)(ws);                          // 32 MB  [32768][512]
  bf16* wT = (bf16*)(ws + ((size_t)32 << 20));     // 1.5 MB [1536][512]
  bf16* qh = (bf16*)(ws + ((size_t)34 << 20));     // 32 MB  [64][4096][64]
  bf16* kt = (bf16*)(ws + ((size_t)66 << 20));     // 32 MB  [64][64][4096]
  bf16* vt = (bf16*)(ws + ((size_t)98 << 20));     // 32 MB  [64][64][4096]
  float* dTp = (float*)(ws);                       // 16 MB, overlaps xb (dead after GEMM)
  bf16* dTb  = (bf16*)(ws + ((size_t)17 << 20));   // 0.5 MB, also inside old xb region

  k_cast_x<<<8192, 256, 0, stream>>>(x, xb);
  k_prep_w<<<3072, 256, 0, stream>>>(wq, wT);
  k_qkv_gemm<<<dim3(12, 256), 256, 0, stream>>>(xb, wT, qg, qb, kg, kb, qh, kt, vt);
  k_dots<<<dim3(16, 64), 64, 0, stream>>>(vt, kt, dTp);
  k_cvt_dt<<<1024, 256, 0, stream>>>(dTp, dTb);
  k_out<<<dim3(32, 64), 256, 0, stream>>>(qh, dTb, out);
}

// Round 2
// 125.784 us; speedup vs baseline: 1.1976x; 1.1976x over previous
//
#include <hip/hip_runtime.h>
#include <hip/hip_bf16.h>
#include <stdint.h>

typedef __bf16 bf16;
typedef __bf16 bf16x8 __attribute__((ext_vector_type(8)));
typedef __bf16 bf16x4 __attribute__((ext_vector_type(4)));
typedef float  f32x4  __attribute__((ext_vector_type(4)));
typedef unsigned int u32;

typedef __attribute__((address_space(1))) u32 gu32;
typedef __attribute__((address_space(3))) u32 lu32;

__device__ __forceinline__ void gld_lds16(const void* g, void* l) {
  __builtin_amdgcn_global_load_lds((gu32*)(uintptr_t)g, (lu32*)(u32)(uintptr_t)l, 16, 0, 0);
}

__device__ __forceinline__ f32x4 mfma_bf16_16x16x32(bf16x8 a, bf16x8 b, f32x4 c) {
  return __builtin_amdgcn_mfma_f32_16x16x32_bf16(a, b, c, 0, 0, 0);
}

#define WAITL_FENCE do { asm volatile("s_waitcnt lgkmcnt(0)" ::: "memory"); \
                         __builtin_amdgcn_sched_barrier(0); } while (0)
#define BARRIER __builtin_amdgcn_s_barrier()

// ---------------- cast x (fp32 -> bf16), 8 elems/thread ----------------
__global__ __launch_bounds__(256) void k_cast_x(const float* __restrict__ x,
                                                bf16* __restrict__ xb) {
  size_t i = (size_t)blockIdx.x * 256 + threadIdx.x;
  const float4* p = (const float4*)x + i * 2;
  float4 a = p[0], b = p[1];
  bf16x8 o;
  o[0] = (bf16)a.x; o[1] = (bf16)a.y; o[2] = (bf16)a.z; o[3] = (bf16)a.w;
  o[4] = (bf16)b.x; o[5] = (bf16)b.y; o[6] = (bf16)b.z; o[7] = (bf16)b.w;
  *(bf16x8*)(xb + i * 8) = o;
}

// ---------------- transpose w [512][1536] f32 -> wT [1536][512] bf16 ----------------
__global__ __launch_bounds__(256) void k_prep_w(const float* __restrict__ w,
                                                bf16* __restrict__ wT) {
  int idx = blockIdx.x * 256 + threadIdx.x;
  int n = idx >> 9;
  int k = idx & 511;
  wT[idx] = (bf16)w[k * 1536 + n];
}

// MFMA quadrant: compile-time (MH, NH)
template <int MH, int NH>
__device__ __forceinline__ void mfma_phase(f32x4 (&acc)[8][4],
                                           const bf16x8 (&afr)[4][2],
                                           const bf16x8 (&bfr)[2][2][2]) {
#pragma unroll
  for (int fm = 0; fm < 4; ++fm)
#pragma unroll
    for (int fn = 0; fn < 2; ++fn)
#pragma unroll
      for (int ks = 0; ks < 2; ++ks)
        acc[MH * 4 + fm][NH * 2 + fn] =
            mfma_bf16_16x16x32(afr[fm][ks], bfr[NH][fn][ks], acc[MH * 4 + fm][NH * 2 + fn]);
}

// ---------------- QKV GEMM: 256x256 tile, BK=64, 8 waves, 8-phase schedule ----
// A = xb [32768][512], Bt = wT [1536][512]. Epilogue as before (q LN, k LN^T, v^T).
// LDS (128 KiB dynamic): A slots: [buf][slot] 4 x 16KB at elem (buf*2+slot)*8192;
//                        B slots: same, at elem 32768 + (buf*2+slot)*8192.
// A slot s holds tile rows with ((row>>6)&1)==s ; B slot s: ((row>>5)&1)==s.
// Phase q=(mh,nh) reads only A-slot mh / B-slot nh across ALL waves.
__global__ __launch_bounds__(512, 2) void k_qkv_gemm(
    const bf16* __restrict__ A, const bf16* __restrict__ Bt,
    const float* __restrict__ qg, const float* __restrict__ qbeta,
    const float* __restrict__ kg, const float* __restrict__ kbeta,
    bf16* __restrict__ qh, bf16* __restrict__ kt, bf16* __restrict__ vt)
{
  extern __shared__ bf16 lds[];
  const int tid = threadIdx.x;
  const int lane = tid & 63;
  const int w = tid >> 6;        // 0..7
  const int wm = w >> 2;         // 0..1
  const int wn = w & 3;          // 0..3

  // XCD-bijective swizzle: 768 blocks = 8 XCDs x 96; tn-major within XCD.
  const int wg = blockIdx.x;
  const int swz = (wg & 7) * 96 + (wg >> 3);
  const int tn = swz % 6;
  const int tm = swz / 6;

  // stage one half-slot (2 x gld_lds, 16 KB) — LDS linear, source pre-swizzled:
  // within each 128B row vr, phys 16B-block p holds source k-block p^(vr&7).
  auto stA = [&](int buf, int slot, int ktile) {
#pragma unroll
    for (int i = 0; i < 2; ++i) {
      int vr = i * 64 + w * 8 + (lane >> 3);
      int grow = tm * 256 + (vr >> 6) * 128 + slot * 64 + (vr & 63);
      int gk = ktile * 64 + (((lane & 7) ^ (vr & 7)) * 8);
      gld_lds16(A + (size_t)grow * 512 + gk,
                (char*)lds + (buf * 2 + slot) * 16384 + i * 8192 + w * 1024);
    }
  };
  auto stB = [&](int buf, int slot, int ktile) {
#pragma unroll
    for (int i = 0; i < 2; ++i) {
      int vr = i * 64 + w * 8 + (lane >> 3);
      int grow = tn * 256 + (vr >> 5) * 64 + slot * 32 + (vr & 31);
      int gk = ktile * 64 + (((lane & 7) ^ (vr & 7)) * 8);
      gld_lds16(Bt + (size_t)grow * 512 + gk,
                (char*)lds + 65536 + (buf * 2 + slot) * 16384 + i * 8192 + w * 1024);
    }
  };
  auto rdA = [&](int buf, int mh, bf16x8 (&fr)[4][2]) {
    const bf16* base = lds + (buf * 2 + mh) * 8192;
#pragma unroll
    for (int f = 0; f < 4; ++f) {
      int vr = wm * 64 + f * 16 + (lane & 15);
#pragma unroll
      for (int ks = 0; ks < 2; ++ks) {
        int pb = (ks * 4 + (lane >> 4)) ^ (vr & 7);
        fr[f][ks] = *(const bf16x8*)(base + vr * 64 + pb * 8);
      }
    }
  };
  auto rdB = [&](int buf, int nh, bf16x8 (&fr)[2][2]) {
    const bf16* base = lds + 32768 + (buf * 2 + nh) * 8192;
#pragma unroll
    for (int f = 0; f < 2; ++f) {
      int vr = wn * 32 + f * 16 + (lane & 15);
#pragma unroll
      for (int ks = 0; ks < 2; ++ks) {
        int pb = (ks * 4 + (lane >> 4)) ^ (vr & 7);
        fr[f][ks] = *(const bf16x8*)(base + vr * 64 + pb * 8);
      }
    }
  };

  bf16x8 afr[4][2];
  bf16x8 bfr[2][2][2];
  f32x4 acc[8][4] = {};

  // prologue: fully stage tiles 0 and 1 (16 loads); let tile1's 8 remain in flight
  stA(0, 0, 0); stB(0, 0, 0); stA(0, 1, 0); stB(0, 1, 0);
  stA(1, 0, 1); stB(1, 0, 1); stA(1, 1, 1); stB(1, 1, 1);
  asm volatile("s_waitcnt vmcnt(8)" ::: "memory");
  BARRIER;

  for (int t = 0; t < 8; ++t) {
    const int d = t & 1;
    // ---- P0 (mh0,nh0): read A0+B0; stage A1(t+1) -> buf d^1
    rdA(d, 0, afr);
    rdB(d, 0, bfr[0]);
    if (t >= 1 && t <= 6) stA(d ^ 1, 1, t + 1);
    BARRIER;
    WAITL_FENCE;
    __builtin_amdgcn_s_setprio(1);
    mfma_phase<0, 0>(acc, afr, bfr);
    __builtin_amdgcn_s_setprio(0);
    BARRIER;
    // ---- P1 (mh0,nh1): read B1; stage B1(t+1) -> buf d^1
    rdB(d, 1, bfr[1]);
    if (t >= 1 && t <= 6) stB(d ^ 1, 1, t + 1);
    BARRIER;
    WAITL_FENCE;
    __builtin_amdgcn_s_setprio(1);
    mfma_phase<0, 1>(acc, afr, bfr);
    __builtin_amdgcn_s_setprio(0);
    BARRIER;
    // ---- P2 (mh1,nh0): read A1; stage A0(t+2) -> buf d
    rdA(d, 1, afr);
    if (t <= 5) stA(d, 0, t + 2);
    BARRIER;
    WAITL_FENCE;
    __builtin_amdgcn_s_setprio(1);
    mfma_phase<1, 0>(acc, afr, bfr);
    __builtin_amdgcn_s_setprio(0);
    BARRIER;
    // ---- P3 (mh1,nh1): no reads; stage B0(t+2) -> buf d; per-tile counted vmcnt
    if (t <= 5) stB(d, 0, t + 2);
    BARRIER;
    __builtin_amdgcn_s_setprio(1);
    mfma_phase<1, 1>(acc, afr, bfr);
    __builtin_amdgcn_s_setprio(0);
    if (t < 6) {
      asm volatile("s_waitcnt vmcnt(4)" ::: "memory");   // all of tile t+1 landed
    } else if (t == 6) {
      asm volatile("s_waitcnt vmcnt(0)" ::: "memory");   // tail: tile 7 fully landed
    }
    BARRIER;                                             // publishes DMA to all waves
  }

  // ---- epilogue: wave owns 128 rows x one 64-col head block ----
  const int colbase = tn * 256 + wn * 64;
  const int part = colbase >> 9;           // 0=q 1=k 2=v
  const int hcol = (colbase >> 6) & 7;     // head
  const int dlane = lane & 15;
  const int rsub = (lane >> 4) * 4;

  if (part == 2) {  // v: no LN, store transposed [bh][d][n]
#pragma unroll
    for (int m = 0; m < 8; ++m) {
      int rowg = tm * 256 + wm * 128 + m * 16 + rsub;
      int bb = rowg >> 12, n0 = rowg & 4095;
      size_t bh64 = (size_t)(bb * 8 + hcol) * 64;
#pragma unroll
      for (int fn = 0; fn < 4; ++fn) {
        bf16x4 pk;
#pragma unroll
        for (int r = 0; r < 4; ++r) pk[r] = (bf16)acc[m][fn][r];
        *(bf16x4*)(vt + (bh64 + fn * 16 + dlane) * 4096 + n0) = pk;
      }
    }
  } else {
    const float* gamma = (part == 0) ? qg : kg;
    const float* beta  = (part == 0) ? qbeta : kbeta;
    float g4[4], b4[4];
#pragma unroll
    for (int fn = 0; fn < 4; ++fn) {
      g4[fn] = gamma[fn * 16 + dlane];
      b4[fn] = beta[fn * 16 + dlane];
    }
#pragma unroll
    for (int m = 0; m < 8; ++m) {
      float mu[4], rs[4];
#pragma unroll
      for (int r = 0; r < 4; ++r) {
        float s  = acc[m][0][r] + acc[m][1][r] + acc[m][2][r] + acc[m][3][r];
        float s2 = acc[m][0][r] * acc[m][0][r] + acc[m][1][r] * acc[m][1][r]
                 + acc[m][2][r] * acc[m][2][r] + acc[m][3][r] * acc[m][3][r];
#pragma unroll
        for (int msk = 1; msk < 16; msk <<= 1) {
          s  += __shfl_xor(s, msk, 64);
          s2 += __shfl_xor(s2, msk, 64);
        }
        float mean = s * (1.0f / 64.0f);
        float var  = s2 * (1.0f / 64.0f) - mean * mean;
        mu[r] = mean;
        rs[r] = rsqrtf(var + 1e-5f);
      }
      int rowg = tm * 256 + wm * 128 + m * 16 + rsub;
      int bb = rowg >> 12, n0 = rowg & 4095;
      int bh = bb * 8 + hcol;
      if (part == 0) {  // q: [bh][n][d]
        bf16* dst = qh + ((size_t)bh * 4096 + n0) * 64;
#pragma unroll
        for (int r = 0; r < 4; ++r)
#pragma unroll
          for (int fn = 0; fn < 4; ++fn) {
            float xv = (acc[m][fn][r] - mu[r]) * rs[r] * g4[fn] + b4[fn];
            dst[(size_t)r * 64 + fn * 16 + dlane] = (bf16)xv;
          }
      } else {          // k: LN, store transposed [bh][d][n]
#pragma unroll
        for (int fn = 0; fn < 4; ++fn) {
          bf16x4 pk;
#pragma unroll
          for (int r = 0; r < 4; ++r)
            pk[r] = (bf16)((acc[m][fn][r] - mu[r]) * rs[r] * g4[fn] + b4[fn]);
          *(bf16x4*)(kt + ((size_t)bh * 64 + fn * 16 + dlane) * 4096 + n0) = pk;
        }
      }
    }
  }
}

// ---------------- dots^T = V^T K per (b,h), split-K=16, deterministic partials ----
__global__ __launch_bounds__(64) void k_dots(const bf16* __restrict__ vt,
                                             const bf16* __restrict__ kt,
                                             float* __restrict__ dTp) {
  __shared__ bf16 lA[64 * 64];
  __shared__ bf16 lB[64 * 64];
  const int lane = threadIdx.x;
  const int bh = blockIdx.y, ch = blockIdx.x;
  const bf16* Ab = vt + (size_t)bh * 64 * 4096 + ch * 256;
  const bf16* Bb = kt + (size_t)bh * 64 * 4096 + ch * 256;
  f32x4 acc[4][4] = {};
  const int srow = lane >> 3;
  const int sblk = (lane & 7) ^ srow;
  for (int ktile = 0; ktile < 4; ++ktile) {
    __syncthreads();
#pragma unroll
    for (int i = 0; i < 8; ++i) {
      int row = i * 8 + srow;
      gld_lds16(Ab + (size_t)row * 4096 + ktile * 64 + sblk * 8, (char*)lA + i * 1024);
      gld_lds16(Bb + (size_t)row * 4096 + ktile * 64 + sblk * 8, (char*)lB + i * 1024);
    }
    __syncthreads();
#pragma unroll
    for (int ks = 0; ks < 2; ++ks) {
      bf16x8 af[4], bq[4];
#pragma unroll
      for (int f = 0; f < 4; ++f) {
        int row = f * 16 + (lane & 15);
        int sb = (ks * 4 + (lane >> 4)) ^ (row & 7);
        af[f] = *(const bf16x8*)(lA + row * 64 + sb * 8);
        bq[f] = *(const bf16x8*)(lB + row * 64 + sb * 8);
      }
#pragma unroll
      for (int fm = 0; fm < 4; ++fm)
#pragma unroll
        for (int fn = 0; fn < 4; ++fn)
          acc[fm][fn] = mfma_bf16_16x16x32(af[fm], bq[fn], acc[fm][fn]);
    }
  }
  float* outp = dTp + (size_t)ch * 262144 + (size_t)bh * 4096;
#pragma unroll
  for (int fm = 0; fm < 4; ++fm)
#pragma unroll
    for (int fn = 0; fn < 4; ++fn)
#pragma unroll
      for (int r = 0; r < 4; ++r) {
        int e = fm * 16 + (lane >> 4) * 4 + r;
        int dd = fn * 16 + (lane & 15);
        outp[e * 64 + dd] = acc[fm][fn][r];
      }
}

// ---------------- reduce split-K partials, cast to bf16 ----------------
__global__ __launch_bounds__(256) void k_cvt_dt(const float* __restrict__ dTp,
                                                bf16* __restrict__ dTb) {
  int i = blockIdx.x * 256 + threadIdx.x;
  float s = 0.f;
#pragma unroll
  for (int c = 0; c < 16; ++c) s += dTp[(size_t)c * 262144 + i];
  dTb[i] = (bf16)s;
}

// ---------------- out = (Q @ dots) / n ----------------
__global__ __launch_bounds__(256) void k_out(const bf16* __restrict__ qh,
                                             const bf16* __restrict__ dTb,
                                             float* __restrict__ out) {
  __shared__ bf16 lA[128 * 64];
  const int tid = threadIdx.x, lane = tid & 63, w = tid >> 6;
  const int wm = w >> 1, wn = w & 1;
  const int bh = blockIdx.y, mt = blockIdx.x;
  const int bb = bh >> 3, h = bh & 7;
  const bf16* Ab = qh + (size_t)bh * 4096 * 64 + (size_t)mt * 128 * 64;
  const int srow = lane >> 3, sblk = (lane & 7) ^ srow;
#pragma unroll
  for (int i = 0; i < 4; ++i) {
    int slot = w * 4 + i;
    int row = slot * 8 + srow;
    gld_lds16(Ab + (size_t)row * 64 + sblk * 8, (char*)lA + slot * 1024);
  }
  __syncthreads();
  const bf16* Bb = dTb + (size_t)bh * 4096;
  f32x4 acc[4][2] = {};
#pragma unroll
  for (int ks = 0; ks < 2; ++ks) {
    bf16x8 af[4], bq[2];
#pragma unroll
    for (int f = 0; f < 4; ++f) {
      int row = wm * 64 + f * 16 + (lane & 15);
      int sb = (ks * 4 + (lane >> 4)) ^ (row & 7);
      af[f] = *(const bf16x8*)(lA + row * 64 + sb * 8);
    }
#pragma unroll
    for (int fn = 0; fn < 2; ++fn) {
      int e = wn * 32 + fn * 16 + (lane & 15);
      bq[fn] = *(const bf16x8*)(Bb + e * 64 + ks * 32 + (lane >> 4) * 8);
    }
#pragma unroll
    for (int fm = 0; fm < 4; ++fm)
#pragma unroll
      for (int fn = 0; fn < 2; ++fn)
        acc[fm][fn] = mfma_bf16_16x16x32(af[fm], bq[fn], acc[fm][fn]);
  }
#pragma unroll
  for (int fm = 0; fm < 4; ++fm)
#pragma unroll
    for (int fn = 0; fn < 2; ++fn)
#pragma unroll
      for (int r = 0; r < 4; ++r) {
        int n = mt * 128 + wm * 64 + fm * 16 + (lane >> 4) * 4 + r;
        int e = wn * 32 + fn * 16 + (lane & 15);
        out[((size_t)bb * 4096 + n) * 512 + h * 64 + e] = acc[fm][fn][r] * (1.0f / 4096.0f);
      }
}

extern "C" void kernel_launch(void* const* d_in, const int* in_sizes, int n_in,
                              void* d_out, int out_size, void* d_ws, size_t ws_size,
                              hipStream_t stream) {
  const float* x  = (const float*)d_in[0];
  const float* wq = (const float*)d_in[1];
  const float* qg = (const float*)d_in[2];
  const float* qb = (const float*)d_in[3];
  const float* kg = (const float*)d_in[4];
  const float* kb = (const float*)d_in[5];
  float* out = (float*)d_out;
  char* ws = (char*)d_ws;

  bf16* xb = (bf16*)(ws);                          // 32 MB  [32768][512]
  bf16* wT = (bf16*)(ws + ((size_t)32 << 20));     // 1.5 MB [1536][512]
  bf16* qh = (bf16*)(ws + ((size_t)34 << 20));     // 32 MB  [64][4096][64]
  bf16* kt = (bf16*)(ws + ((size_t)66 << 20));     // 32 MB  [64][64][4096]
  bf16* vt = (bf16*)(ws + ((size_t)98 << 20));     // 32 MB  [64][64][4096]
  float* dTp = (float*)(ws);                       // 16 MB, overlaps dead xb
  bf16* dTb  = (bf16*)(ws + ((size_t)17 << 20));   // 0.5 MB

  k_cast_x<<<8192, 256, 0, stream>>>(x, xb);
  k_prep_w<<<3072, 256, 0, stream>>>(wq, wT);
  k_qkv_gemm<<<768, 512, 131072, stream>>>(xb, wT, qg, qb, kg, kb, qh, kt, vt);
  k_dots<<<dim3(16, 64), 64, 0, stream>>>(vt, kt, dTp);
  k_cvt_dt<<<1024, 256, 0, stream>>>(dTp, dTb);
  k_out<<<dim3(32, 64), 256, 0, stream>>>(qh, dTb, out);
}